// Round 12
// baseline (454.129 us; speedup 1.0000x reference)
//
#include <hip/hip_runtime.h>

#define DEV __device__ __forceinline__

using f32x4  = __attribute__((ext_vector_type(4))) float;
using bf16x8 = __attribute__((ext_vector_type(8))) __bf16;
using bf16x4 = __attribute__((ext_vector_type(4))) __bf16;

constexpr int Bc = 8, Tc = 2048, Ec = 1024, Hc = 1024;
constexpr int Mc = Bc * Tc;    // 16384 total rows
constexpr int SLOT = 256 * 32; // elements per 16KB khalf sub-slice

DEV f32x4 mfma16(bf16x8 a, bf16x8 b, f32x4 c) {
    return __builtin_amdgcn_mfma_f32_16x16x32_bf16(a, b, c, 0, 0, 0);
}
DEV unsigned short f16bits(float f) { return __builtin_bit_cast(unsigned short, (_Float16)f); }
DEV float f16val(unsigned short u) { return (float)__builtin_bit_cast(_Float16, u); }
DEV unsigned short bf16bits(float f) { return __builtin_bit_cast(unsigned short, (__bf16)f); }

// async global->LDS, 16B per lane. LDS dest must be wave-uniform base; HW adds lane*16.
DEV void gload16(const __bf16* g, __bf16* l) {
    __builtin_amdgcn_global_load_lds(
        (const __attribute__((address_space(1))) unsigned int*)g,
        (__attribute__((address_space(3))) unsigned int*)l, 16, 0, 0);
}

// Paired-row swizzled LDS sub-slice layout (256x32 bf16 = 16KB):
// LDS row r (128B) holds tile-rows {2r, 2r+1}; the 8 16B slots within row r
// are XOR-permuted by (r&7).  Verified 0 bank conflicts (rounds 5-11).
DEV int swz_off(int R, int lk) {
    return ((R >> 1) << 6) + ((((((R & 1) << 2) | lk) ^ ((R >> 1) & 7))) << 3);
}

// ---------------------------------------------------------------------------
// prep_x: split f32 x into hi/lo bf16 (x = hi + lo to ~17 mantissa bits)
// ---------------------------------------------------------------------------
__global__ __launch_bounds__(256) void prep_x(const float* __restrict__ x,
                                              __bf16* __restrict__ xh,
                                              __bf16* __restrict__ xl, int n) {
    int i = (blockIdx.x * 256 + threadIdx.x) * 4;
    if (i >= n) return;
    f32x4 v = *reinterpret_cast<const f32x4*>(x + i);
    bf16x4 h, l;
#pragma unroll
    for (int j = 0; j < 4; j++) {
        __bf16 hv = (__bf16)v[j];
        h[j] = hv;
        l[j] = (__bf16)(v[j] - (float)hv);
    }
    *reinterpret_cast<bf16x4*>(xh + i) = h;
    *reinterpret_cast<bf16x4*>(xl + i) = l;
}

// ---------------------------------------------------------------------------
// prep_w: transpose W[e][n] -> WT[n][e], bf16 hi only.
// Wall[3072][1024]: rows [0,1024)=Wq, [1024,2048)=Wk, [2048,3072)=Wv.
// ---------------------------------------------------------------------------
__global__ __launch_bounds__(256) void prep_w(const float* __restrict__ wq,
                                              const float* __restrict__ wk,
                                              const float* __restrict__ wv,
                                              __bf16* __restrict__ wall) {
    __shared__ float tile[32][33];
    const int z = blockIdx.z;
    const float* src = (z == 0) ? wq : (z == 1) ? wk : wv;
    __bf16* dh = wall + (size_t)z * 1024 * Ec;
    const int n0 = blockIdx.x * 32, e0 = blockIdx.y * 32;
    const int tx = threadIdx.x & 31, ty = threadIdx.x >> 5;  // 32 x 8
#pragma unroll
    for (int j = 0; j < 32; j += 8)
        tile[ty + j][tx] = src[(size_t)(e0 + ty + j) * Hc + n0 + tx];
    __syncthreads();
#pragma unroll
    for (int j = 0; j < 32; j += 8)
        dh[(size_t)(n0 + ty + j) * Ec + e0 + tx] = (__bf16)tile[tx][ty + j];
}

// ---------------------------------------------------------------------------
// gemm_body: 256x256 tile, 8 waves (2x4, each 128x64), 512 threads, BK=64
// tiles, ring-2 LDS (128 KiB), m201-style 4-phase fine interleave.
// Phase q of tile T: { read A frags 2q,2q+1 (4 b128; ph0 also B 8 b128 ->
//   regs, held all 4 phases); wave-specific stage batch; vmcnt(8); barrier;
//   setprio(1); 16 MFMA (frags 2q,2q+1 x n0-3 x kh0,kh1); setprio(0);
//   barrier }.
// Self-buffer staggered staging (tile T+2 -> buf T&1, the one being read):
//   wave (wm,wn) owns A-region = frag-pair wn of half wm (rows wm*128+wn*32,
//   32 rows) + B-rows wave*32.  Region A(f) last read at phase f ->
//   overwrite may issue from phase f+1 on (barrier-separated).
//   wn<3: stage A+B of tile T+2 at phase wn+1.
//   wn=3: A of tile T+1 at phase 0 (targets the OTHER buf; its frags 6,7
//         last read at tile T-1 ph3), B of tile T+2 at phase 1 (B of the
//         current buf fully consumed at ph0).
// Gating: vmcnt(8) before EVERY phase barrier.  Per-wave outstanding is at
//   most its latest 8-load batch (or 4+4 split for wn=3), so vmcnt(8) proves
//   every OLDER batch landed; by induction each region's stage is proven >= 2
//   phase-barriers before its first reader.  Prologue fully drains tiles 0,1
//   (vmcnt 0).  Tail (T >= nkt-3): vmcnt(0) since no newer batch will push
//   the final ones past 8.
// Accumulation order per acc element: kh0 then kh1, tiles in order — BIT-
// IDENTICAL to the round-11 kernel.
// NTERMS==2: virtual K=2048: tiles 0-15 Ah*Bh, 16-31 Al*Bh.
// EPI: 0 = bf16 out, N=2048: Q (gn<1024) hi/lo, K (gn>=1024) hi only
//      1 = bf16 transposed store Vt[b][n][t]
//      2 = f16 causal energy * 1/sqrt(dk)
//      3 = f32 row-major (PV), nkt = (by+1)*4
// ---------------------------------------------------------------------------
template <int NTERMS, int EPI>
DEV void gemm_body(int bx, int by, int z,
                   const __bf16* __restrict__ Ah, const __bf16* __restrict__ Al,
                   const __bf16* __restrict__ Bh,
                   void* __restrict__ out0, void* __restrict__ out1,
                   void* __restrict__ out2, void* __restrict__ out3,
                   const int* __restrict__ dkp,
                   int lda, int ldb, size_t aBS, size_t bBS, size_t oBS, int nkt,
                   __bf16* sAb, __bf16* sBb) {
    if (EPI == 3) nkt = (by + 1) * 4;  // causal K extent (BK=64)

    Ah += (size_t)z * aBS;
    Bh += (size_t)z * bBS;
    if (NTERMS == 2) Al += (size_t)z * aBS;

    const float scale = (EPI == 2) ? (1.0f / sqrtf((float)*dkp)) : 1.0f;

    const int tid = threadIdx.x;
    const int wave = tid >> 6, lane = tid & 63;
    const int lr = lane & 15, lk = lane >> 4;
    const int wm = wave >> 2, wn = wave & 3;  // 2 x 4 wave grid
    const int m0 = by * 256, n0 = bx * 256;

    // staging constants (inverse-swizzled global source, linear LDS dest):
    const int so = (lane & 7) ^ (lane >> 3);
    const int strow = 2 * (lane >> 3) + (so >> 2);
    const int stcol = (so & 3) * 8;

    // stageA(sv): wave's A-region (rows wm*128 + wn*32 .. +32) of tile sv.
    auto stageA = [&](int sv) {
        const __bf16* as = Ah;
        int kk = sv * 64;
        if (NTERMS == 2) { as = (sv >> 4) ? Al : Ah; kk = (sv & 15) * 64; }
        __bf16* dA = sAb + (size_t)(sv & 1) * (2 * SLOT);
#pragma unroll
        for (int kh = 0; kh < 2; kh++)
#pragma unroll
            for (int l = 0; l < 2; l++) {
                const int g = wm * 8 + wn * 2 + l;  // 16-row group index
                gload16(as + (size_t)(m0 + g * 16 + strow) * lda + kk + kh * 32 + stcol,
                        dA + kh * SLOT + g * 512);
            }
    };
    // stageB(sv): wave's B-region (rows wave*32 .. +32) of tile sv.
    auto stageB = [&](int sv) {
        int kk = (NTERMS == 2) ? (sv & 15) * 64 : sv * 64;
        __bf16* dB = sBb + (size_t)(sv & 1) * (2 * SLOT);
#pragma unroll
        for (int kh = 0; kh < 2; kh++)
#pragma unroll
            for (int l = 0; l < 2; l++) {
                const int g = wave * 2 + l;
                gload16(Bh + (size_t)(n0 + g * 16 + strow) * ldb + kk + kh * 32 + stcol,
                        dB + kh * SLOT + g * 512);
            }
    };

    f32x4 acc[8][4] = {};
    bf16x8 bfr[4][2];  // B fragments, read at ph0, live across the tile

    // prologue: tiles 0 and 1 fully staged and drained
    stageA(0); stageB(0);
    stageA(1); stageB(1);
    asm volatile("s_waitcnt vmcnt(0)" ::: "memory");
    __builtin_amdgcn_s_barrier();

    for (int T = 0; T < nkt; ++T) {
        const __bf16* cA = sAb + (size_t)(T & 1) * (2 * SLOT);
        const __bf16* cB = sBb + (size_t)(T & 1) * (2 * SLOT);
        const bool tail = (T >= nkt - 3);

#pragma unroll
        for (int q = 0; q < 4; q++) {
            bf16x8 af[2][2];
#pragma unroll
            for (int i = 0; i < 2; i++)
#pragma unroll
                for (int kh = 0; kh < 2; kh++)
                    af[i][kh] = *reinterpret_cast<const bf16x8*>(
                        &cA[kh * SLOT + swz_off(wm * 128 + (2 * q + i) * 16 + lr, lk)]);
            if (q == 0) {
#pragma unroll
                for (int n = 0; n < 4; n++)
#pragma unroll
                    for (int kh = 0; kh < 2; kh++)
                        bfr[n][kh] = *reinterpret_cast<const bf16x8*>(
                            &cB[kh * SLOT + swz_off(wn * 64 + n * 16 + lr, lk)]);
            }

            // wave-specific staggered staging
            if (wn < 3) {
                if (q == wn + 1 && T + 2 < nkt) { stageA(T + 2); stageB(T + 2); }
            } else {
                if (q == 0 && T >= 1 && T + 1 < nkt) stageA(T + 1);
                if (q == 1 && T + 2 < nkt) stageB(T + 2);
            }

            if (tail) asm volatile("s_waitcnt vmcnt(0)" ::: "memory");
            else      asm volatile("s_waitcnt vmcnt(8)" ::: "memory");
            __builtin_amdgcn_s_barrier();

            __builtin_amdgcn_s_setprio(1);
#pragma unroll
            for (int i = 0; i < 2; i++) {
#pragma unroll
                for (int n = 0; n < 4; n++)
                    acc[2 * q + i][n] = mfma16(af[i][0], bfr[n][0], acc[2 * q + i][n]);
#pragma unroll
                for (int n = 0; n < 4; n++)
                    acc[2 * q + i][n] = mfma16(af[i][1], bfr[n][1], acc[2 * q + i][n]);
            }
            __builtin_amdgcn_s_setprio(0);
            __builtin_amdgcn_s_barrier();
        }
    }

#pragma unroll
    for (int mi = 0; mi < 8; mi++)
#pragma unroll
        for (int nj = 0; nj < 4; nj++) {
            const int gn = n0 + wn * 64 + nj * 16 + lr;
            if (EPI == 1) {
                const int gm0 = m0 + wm * 128 + mi * 16 + lk * 4;
                const int bb = gm0 >> 11, t = gm0 & (Tc - 1);
                bf16x4 pk;
#pragma unroll
                for (int r = 0; r < 4; r++) pk[r] = (__bf16)acc[mi][nj][r];
                *reinterpret_cast<bf16x4*>(
                    &((__bf16*)out0)[((size_t)(bb * Hc + gn)) * Tc + t]) = pk;
            } else if (EPI == 0) {
                __bf16* oh = (gn < 1024) ? (__bf16*)out0 : (__bf16*)out2;
                __bf16* ol = (gn < 1024) ? (__bf16*)out1 : (__bf16*)out3;
                const int cc = gn & 1023;
#pragma unroll
                for (int r = 0; r < 4; r++) {
                    const int gm = m0 + wm * 128 + mi * 16 + lk * 4 + r;
                    const float v = acc[mi][nj][r];
                    __bf16 h = (__bf16)v;
                    oh[(size_t)gm * Hc + cc] = h;
                    if (ol) ol[(size_t)gm * Hc + cc] = (__bf16)(v - (float)h);
                }
            } else {
#pragma unroll
                for (int r = 0; r < 4; r++) {
                    const int gm = m0 + wm * 128 + mi * 16 + lk * 4 + r;
                    const float v = acc[mi][nj][r];
                    if (EPI == 2) {
                        const float e = (gn > gm) ? -INFINITY : v * scale;
                        ((unsigned short*)out0)[(size_t)z * oBS + (size_t)gm * Tc + gn] =
                            f16bits(e);
                    } else {
                        ((float*)out0)[(size_t)z * oBS + (size_t)gm * Hc + gn] = v;
                    }
                }
            }
        }
}

// ---------------------------------------------------------------------------
// k_qkv: QK-projection (512 blocks, 32 tiles) + V-projection (256 blocks,
// 16 tiles).  launch_bounds(512,2): do NOT tighten — (512,4) spilled acc
// to scratch (round 8: 5.8 GB traffic, 9x slowdown).
// ---------------------------------------------------------------------------
__global__ __launch_bounds__(512, 2) void k_qkv(
        const __bf16* __restrict__ Xh, const __bf16* __restrict__ Xl,
        const __bf16* __restrict__ Wall,
        __bf16* __restrict__ Qh, __bf16* __restrict__ Ql,
        __bf16* __restrict__ Kh, __bf16* __restrict__ Vt,
        const int* __restrict__ dkp) {
    __shared__ __bf16 sA[2][2][SLOT];  // 64 KiB
    __shared__ __bf16 sB[2][2][SLOT];  // 64 KiB
    const int i = blockIdx.x;
    if (i < 512) {
        // QK proj: bijective XCD chunking over the (8 x 64) tile grid
        const int w = (i & 7) * 64 + (i >> 3);
        const int by = w >> 3, bx = w & 7;
        gemm_body<2, 0>(bx, by, 0, Xh, Xl, Wall, Qh, Ql, Kh, nullptr, dkp,
                        Ec, Ec, 0, 0, 0, 32, sA[0][0], sB[0][0]);
    } else {
        const int j = i - 512;  // V proj: (4 x 64) tile grid
        gemm_body<1, 1>(j & 3, j >> 2, 0, Xh, nullptr, Wall + (size_t)2048 * Ec,
                        Vt, nullptr, nullptr, nullptr, dkp,
                        Ec, Ec, 0, 0, 0, 16, sA[0][0], sB[0][0]);
    }
}

// ---------------------------------------------------------------------------
// k_energy: 288 causal tiles (36 per batch), 32 K-tiles each.
// ---------------------------------------------------------------------------
__global__ __launch_bounds__(512, 2) void k_energy(
        const __bf16* __restrict__ Qh, const __bf16* __restrict__ Ql,
        const __bf16* __restrict__ Kh, unsigned short* __restrict__ S,
        const int* __restrict__ dkp) {
    __shared__ __bf16 sA[2][2][SLOT];
    __shared__ __bf16 sB[2][2][SLOT];
    const int i = blockIdx.x;
    const int b = i / 36;
    int t = i - b * 36;
    int by = 0;
    while (t >= by + 1) { t -= by + 1; by++; }  // triangle decode: bx=t <= by
    gemm_body<2, 2>(t, by, b, Qh, Ql, Kh, S, nullptr, nullptr, nullptr, dkp,
                    Hc, Hc, (size_t)Tc * Hc, (size_t)Tc * Hc, (size_t)Tc * Tc, 32,
                    sA[0][0], sB[0][0]);
}

// ---------------------------------------------------------------------------
// k_pv: PV, grid (4, 8, batch); nkt = (by+1)*4 inside body.
// ---------------------------------------------------------------------------
__global__ __launch_bounds__(512, 2) void k_pv(
        const __bf16* __restrict__ S, const __bf16* __restrict__ Vt,
        float* __restrict__ out, const int* __restrict__ dkp) {
    __shared__ __bf16 sA[2][2][SLOT];
    __shared__ __bf16 sB[2][2][SLOT];
    gemm_body<1, 3>(blockIdx.x, blockIdx.y, blockIdx.z, S, nullptr, Vt,
                    out, nullptr, nullptr, nullptr, dkp,
                    Tc, Tc, (size_t)Tc * Tc, (size_t)Hc * Tc, (size_t)Tc * Hc, 0,
                    sA[0][0], sB[0][0]);
}

// ---------------------------------------------------------------------------
// softmax_k: one block per (b,q) row.  Reads f16 logits, writes bf16 P in
// place.  Threads beyond the tile-aligned causal extent skip their loads and
// stores entirely (PV's K-extent is (q/256+1)*256, so those cols are never
// read) but still participate in all reductions/barriers.
// ---------------------------------------------------------------------------
__global__ __launch_bounds__(256) void softmax_k(unsigned short* __restrict__ S) {
    const int q = blockIdx.x & (Tc - 1);
    const int b = blockIdx.x >> 11;
    const int tid = threadIdx.x;
    const int c0 = tid * 8;
    const int limit = ((q >> 8) + 1) << 8;  // tile-aligned causal extent
    const bool active = c0 < limit;
    unsigned short* row = S + ((size_t)b * Tc + q) * Tc;

    float v[8];
    if (active) {
        uint4 raw = *reinterpret_cast<const uint4*>(row + c0);
        unsigned u[4] = {raw.x, raw.y, raw.z, raw.w};
#pragma unroll
        for (int p = 0; p < 4; p++) {
            v[2 * p]     = f16val((unsigned short)(u[p] & 0xFFFFu));
            v[2 * p + 1] = f16val((unsigned short)(u[p] >> 16));
        }
#pragma unroll
        for (int i = 0; i < 8; i++)
            if (c0 + i > q) v[i] = -INFINITY;
    } else {
#pragma unroll
        for (int i = 0; i < 8; i++) v[i] = -INFINITY;
    }

    float m = v[0];
#pragma unroll
    for (int i = 1; i < 8; i++) m = fmaxf(m, v[i]);
#pragma unroll
    for (int off = 1; off < 64; off <<= 1) m = fmaxf(m, __shfl_xor(m, off));
    __shared__ float red[4];
    if ((tid & 63) == 0) red[tid >> 6] = m;
    __syncthreads();
    m = fmaxf(fmaxf(red[0], red[1]), fmaxf(red[2], red[3]));

    float e[8], s = 0.f;
#pragma unroll
    for (int i = 0; i < 8; i++) {
        e[i] = __expf(v[i] - m);  // exp(-inf)=0
        s += e[i];
    }
#pragma unroll
    for (int off = 1; off < 64; off <<= 1) s += __shfl_xor(s, off);
    __syncthreads();
    if ((tid & 63) == 0) red[tid >> 6] = s;
    __syncthreads();
    s = red[0] + red[1] + red[2] + red[3];
    const float inv = 1.0f / s;

    if (active) {
        unsigned o[4];
#pragma unroll
        for (int p = 0; p < 4; p++) {
            unsigned short a = bf16bits(e[2 * p] * inv);
            unsigned short bb = bf16bits(e[2 * p + 1] * inv);
            o[p] = (unsigned)a | ((unsigned)bb << 16);
        }
        uint4 w; w.x = o[0]; w.y = o[1]; w.z = o[2]; w.w = o[3];
        *reinterpret_cast<uint4*>(row + c0) = w;
    }
}

// ---------------------------------------------------------------------------
extern "C" void kernel_launch(void* const* d_in, const int* in_sizes, int n_in,
                              void* d_out, int out_size, void* d_ws, size_t ws_size,
                              hipStream_t stream) {
    const float* x  = (const float*)d_in[0];
    const float* Wq = (const float*)d_in[1];
    const float* Wk = (const float*)d_in[2];
    const float* Wv = (const float*)d_in[3];
    const int*   dk = (const int*)d_in[4];
    float* out = (float*)d_out;
    char* ws = (char*)d_ws;

    const size_t SZ_XE = (size_t)Mc * Ec * 2;  // 32 MiB
    const size_t SZ_W  = (size_t)Ec * Hc * 2;  // 2 MiB

    size_t o = 0;
    auto nxt = [&](size_t bytes) { void* p = ws + o; o += bytes; return p; };
    __bf16* Xh   = (__bf16*)nxt(SZ_XE);
    __bf16* Xl   = (__bf16*)nxt(SZ_XE);
    __bf16* Wall = (__bf16*)nxt(3 * SZ_W);  // [3072][1024] = Wq|Wk|Wv hi, transposed
    __bf16* Qh   = (__bf16*)nxt(SZ_XE);
    __bf16* Ql   = (__bf16*)nxt(SZ_XE);
    __bf16* Kh   = (__bf16*)nxt(SZ_XE);
    __bf16* Vt   = (__bf16*)nxt(SZ_XE);
    // S: all-batch f16 [8][2048][2048] = 64 MiB, aliases Xh+Xl (both dead
    // after k_qkv completes; k_energy is stream-ordered after it)
    unsigned short* S = (unsigned short*)Xh;
    (void)ws_size; (void)in_sizes; (void)n_in; (void)out_size;

    prep_x<<<(Mc * Ec / 4 + 255) / 256, 256, 0, stream>>>(x, Xh, Xl, Mc * Ec);
    prep_w<<<dim3(32, 32, 3), 256, 0, stream>>>(Wq, Wk, Wv, Wall);

    // QK proj (2-term, Q hi/lo + K hi) and V proj (1-term, transposed) combined
    k_qkv<<<768, 512, 0, stream>>>(Xh, Xl, Wall, Qh, Ql, Kh, Vt, dk);

    // energy: 288 causal tiles, f16 logits, virtual K=2048 (QhKh + QlKh)
    k_energy<<<288, 512, 0, stream>>>(Qh, Ql, Kh, S, dk);

    softmax_k<<<Bc * Tc, 256, 0, stream>>>(S);

    // PV: nkt=(by+1)*4 per tile (P beyond causal edge is 0)
    k_pv<<<dim3(4, 8, Bc), 512, 0, stream>>>((const __bf16*)S, Vt, out, dk);
}

// Round 13
// 287.320 us; speedup vs baseline: 1.5806x; 1.5806x over previous
//
#include <hip/hip_runtime.h>

#define DEV __device__ __forceinline__

using f32x4 = __attribute__((ext_vector_type(4))) float;
using f16x8 = __attribute__((ext_vector_type(8))) _Float16;
using f16x4 = __attribute__((ext_vector_type(4))) _Float16;

constexpr int Bc = 8, Tc = 2048, Ec = 1024, Hc = 1024;
constexpr int Mc = Bc * Tc;    // 16384 total rows
constexpr int SLOT = 256 * 32; // elements per 16KB slice

DEV f32x4 mfma16(f16x8 a, f16x8 b, f32x4 c) {
    return __builtin_amdgcn_mfma_f32_16x16x32_f16(a, b, c, 0, 0, 0);
}
DEV unsigned short f16bits(float f) { return __builtin_bit_cast(unsigned short, (_Float16)f); }
DEV float f16val(unsigned short u) { return (float)__builtin_bit_cast(_Float16, u); }

// async global->LDS, 16B per lane. LDS dest must be wave-uniform base; HW adds lane*16.
DEV void gload16(const _Float16* g, _Float16* l) {
    __builtin_amdgcn_global_load_lds(
        (const __attribute__((address_space(1))) unsigned int*)g,
        (__attribute__((address_space(3))) unsigned int*)l, 16, 0, 0);
}

// Paired-row swizzled LDS slice layout (256x32 f16 = 16KB):
// LDS row r (128B) holds tile-rows {2r, 2r+1}; the 8 16B slots within row r
// are XOR-permuted by (r&7).  Verified 0 bank conflicts (rounds 5-12; element
// size unchanged bf16->f16).
DEV int swz_off(int R, int lk) {
    return ((R >> 1) << 6) + ((((((R & 1) << 2) | lk) ^ ((R >> 1) & 7))) << 3);
}

// ---------------------------------------------------------------------------
// prep_x: f32 x -> f16 (11-bit mantissa; see round-12 error audit)
// ---------------------------------------------------------------------------
__global__ __launch_bounds__(256) void prep_x(const float* __restrict__ x,
                                              _Float16* __restrict__ xf, int n) {
    int i = (blockIdx.x * 256 + threadIdx.x) * 4;
    if (i >= n) return;
    f32x4 v = *reinterpret_cast<const f32x4*>(x + i);
    f16x4 h;
#pragma unroll
    for (int j = 0; j < 4; j++) h[j] = (_Float16)v[j];
    *reinterpret_cast<f16x4*>(xf + i) = h;
}

// ---------------------------------------------------------------------------
// prep_w: transpose W[e][n] -> WT[n][e], f16.
// Wall[3072][1024]: rows [0,1024)=Wq, [1024,2048)=Wk, [2048,3072)=Wv.
// ---------------------------------------------------------------------------
__global__ __launch_bounds__(256) void prep_w(const float* __restrict__ wq,
                                              const float* __restrict__ wk,
                                              const float* __restrict__ wv,
                                              _Float16* __restrict__ wall) {
    __shared__ float tile[32][33];
    const int z = blockIdx.z;
    const float* src = (z == 0) ? wq : (z == 1) ? wk : wv;
    _Float16* dh = wall + (size_t)z * 1024 * Ec;
    const int n0 = blockIdx.x * 32, e0 = blockIdx.y * 32;
    const int tx = threadIdx.x & 31, ty = threadIdx.x >> 5;  // 32 x 8
#pragma unroll
    for (int j = 0; j < 32; j += 8)
        tile[ty + j][tx] = src[(size_t)(e0 + ty + j) * Hc + n0 + tx];
    __syncthreads();
#pragma unroll
    for (int j = 0; j < 32; j += 8)
        dh[(size_t)(n0 + ty + j) * Ec + e0 + tx] = (_Float16)tile[tx][ty + j];
}

// ---------------------------------------------------------------------------
// gemm_body: round-10 schedule (best measured: 45.7% MfmaUtil) — 256x256
// tile, 8 waves (2x4, each 128x64), 512 threads, BK=32 slots, ring-3 LDS
// (96 KiB), ONE barrier per slot:
//   { 12 ds_read (bfr then af); stage(P+2) -> slot (P+2)%3;
//     setprio(1); 32 MFMA; setprio(0); vmcnt(4); s_barrier }
// Counted vmcnt(4): stage(P+2)'s 4 loads may stay in flight; stage(P+1)
// (issued in slot P-1) is proven complete at the slot exit.
// All GEMMs single-term f16 (no hi/lo split — f16's 11-bit mantissa beats
// the old 2-term bf16 split at every stage; round-12 error audit).
// EPI: 0 = f16 out, N=2048: Q (gn<1024) / K (gn>=1024)
//      1 = f16 transposed store Vt[b][n][t]
//      2 = f16 causal energy * 1/sqrt(dk)
//      3 = f32 row-major (PV), nkt = (by+1)*8
// ---------------------------------------------------------------------------
template <int EPI>
DEV void gemm_body(int bx, int by, int z,
                   const _Float16* __restrict__ Ah, const _Float16* __restrict__ Bh,
                   void* __restrict__ out0, void* __restrict__ out2,
                   const int* __restrict__ dkp,
                   int lda, int ldb, size_t aBS, size_t bBS, size_t oBS, int nkt,
                   _Float16* sAb, _Float16* sBb) {
    if (EPI == 3) nkt = (by + 1) * 8;  // causal K extent (BK=32)

    Ah += (size_t)z * aBS;
    Bh += (size_t)z * bBS;

    const float scale = (EPI == 2) ? (1.0f / sqrtf((float)*dkp)) : 1.0f;

    const int tid = threadIdx.x;
    const int wave = tid >> 6, lane = tid & 63;
    const int lr = lane & 15, lk = lane >> 4;
    const int wm = wave >> 2, wn = wave & 3;  // 2 x 4 wave grid
    const int m0 = by * 256, n0 = bx * 256;

    // staging constants (inverse-swizzled global source, linear LDS dest):
    const int so = (lane & 7) ^ (lane >> 3);
    const int strow = 2 * (lane >> 3) + (so >> 2);
    const int stcol = (so & 3) * 8;
    const size_t aoff0 = (size_t)(m0 + (wave * 2 + 0) * 16 + strow) * lda + stcol;
    const size_t aoff1 = (size_t)(m0 + (wave * 2 + 1) * 16 + strow) * lda + stcol;
    const size_t boff0 = (size_t)(n0 + (wave * 2 + 0) * 16 + strow) * ldb + stcol;
    const size_t boff1 = (size_t)(n0 + (wave * 2 + 1) * 16 + strow) * ldb + stcol;
    const int ld0 = (wave * 2 + 0) * 512, ld1 = (wave * 2 + 1) * 512;

    auto stage = [&](int sv, int slot) {
        const int kk = sv * 32;
        _Float16* dA = sAb + slot * SLOT;
        _Float16* dB = sBb + slot * SLOT;
        gload16(Ah + aoff0 + kk, dA + ld0);
        gload16(Ah + aoff1 + kk, dA + ld1);
        gload16(Bh + boff0 + kk, dB + ld0);
        gload16(Bh + boff1 + kk, dB + ld1);
    };

    f32x4 acc[8][4] = {};

    // prologue: slots 0 and 1 in flight; gate slot 0 (allow slot 1's 4 loads)
    stage(0, 0);
    stage(1, 1);
    asm volatile("s_waitcnt vmcnt(4)" ::: "memory");
    __builtin_amdgcn_s_barrier();

    int rP = 0;  // P % 3
    for (int P = 0; P < nkt; ++P) {
        const _Float16* cA = sAb + rP * SLOT;
        const _Float16* cB = sBb + rP * SLOT;
        f16x8 af[8], bfr[4];

        // B frags first so the first MFMA's operands arrive earliest
#pragma unroll
        for (int nj = 0; nj < 4; nj++)
            bfr[nj] = *reinterpret_cast<const f16x8*>(
                &cB[swz_off(wn * 64 + nj * 16 + lr, lk)]);
#pragma unroll
        for (int mi = 0; mi < 8; mi++)
            af[mi] = *reinterpret_cast<const f16x8*>(
                &cA[swz_off(wm * 128 + mi * 16 + lr, lk)]);

        int rs = rP + 2; if (rs >= 3) rs -= 3;
        if (P + 2 < nkt) stage(P + 2, rs);

        __builtin_amdgcn_s_setprio(1);
#pragma unroll
        for (int mi = 0; mi < 8; mi++)
#pragma unroll
            for (int nj = 0; nj < 4; nj++)
                acc[mi][nj] = mfma16(af[mi], bfr[nj], acc[mi][nj]);
        __builtin_amdgcn_s_setprio(0);

        // slot-exit gate: stage(P+1) must be complete (counted; never 0 in
        // steady state).  Skip entirely on the last slot.
        if (P + 2 < nkt) {
            asm volatile("s_waitcnt vmcnt(4)" ::: "memory");
            __builtin_amdgcn_s_barrier();
        } else if (P + 1 < nkt) {
            asm volatile("s_waitcnt vmcnt(0)" ::: "memory");
            __builtin_amdgcn_s_barrier();
        }
        if (++rP == 3) rP = 0;
    }

#pragma unroll
    for (int mi = 0; mi < 8; mi++)
#pragma unroll
        for (int nj = 0; nj < 4; nj++) {
            const int gn = n0 + wn * 64 + nj * 16 + lr;
            if (EPI == 1) {
                const int gm0 = m0 + wm * 128 + mi * 16 + lk * 4;
                const int bb = gm0 >> 11, t = gm0 & (Tc - 1);
                f16x4 pk;
#pragma unroll
                for (int r = 0; r < 4; r++) pk[r] = (_Float16)acc[mi][nj][r];
                *reinterpret_cast<f16x4*>(
                    &((_Float16*)out0)[((size_t)(bb * Hc + gn)) * Tc + t]) = pk;
            } else if (EPI == 0) {
                _Float16* od = (gn < 1024) ? (_Float16*)out0 : (_Float16*)out2;
                const int cc = gn & 1023;
#pragma unroll
                for (int r = 0; r < 4; r++) {
                    const int gm = m0 + wm * 128 + mi * 16 + lk * 4 + r;
                    od[(size_t)gm * Hc + cc] = (_Float16)acc[mi][nj][r];
                }
            } else {
#pragma unroll
                for (int r = 0; r < 4; r++) {
                    const int gm = m0 + wm * 128 + mi * 16 + lk * 4 + r;
                    const float v = acc[mi][nj][r];
                    if (EPI == 2) {
                        const float e = (gn > gm) ? -INFINITY : v * scale;
                        ((unsigned short*)out0)[(size_t)z * oBS + (size_t)gm * Tc + gn] =
                            f16bits(e);
                    } else {
                        ((float*)out0)[(size_t)z * oBS + (size_t)gm * Hc + gn] = v;
                    }
                }
            }
        }
}

// ---------------------------------------------------------------------------
// k_qkv: QK-projection (512 blocks) + V-projection (256 blocks), all K=1024
// (32 slots).  launch_bounds(512,2): do NOT tighten — (512,4) spilled acc to
// scratch (round 8: 5.8 GB traffic, 9x slowdown).
// ---------------------------------------------------------------------------
__global__ __launch_bounds__(512, 2) void k_qkv(
        const _Float16* __restrict__ Xf, const _Float16* __restrict__ Wall,
        _Float16* __restrict__ Qf, _Float16* __restrict__ Kf,
        _Float16* __restrict__ Vt, const int* __restrict__ dkp) {
    __shared__ _Float16 sA[3][SLOT];  // 48 KiB
    __shared__ _Float16 sB[3][SLOT];  // 48 KiB
    const int i = blockIdx.x;
    if (i < 512) {
        // QK proj: bijective XCD chunking over the (8 x 64) tile grid
        const int w = (i & 7) * 64 + (i >> 3);
        const int by = w >> 3, bx = w & 7;
        gemm_body<0>(bx, by, 0, Xf, Wall, Qf, Kf, dkp,
                     Ec, Ec, 0, 0, 0, 32, sA[0], sB[0]);
    } else {
        const int j = i - 512;  // V proj: (4 x 64) tile grid
        gemm_body<1>(j & 3, j >> 2, 0, Xf, Wall + (size_t)2048 * Ec,
                     Vt, nullptr, dkp, Ec, Ec, 0, 0, 0, 32, sA[0], sB[0]);
    }
}

// ---------------------------------------------------------------------------
// k_energy: 288 causal tiles (36 per batch), single-term f16, 32 slots.
// ---------------------------------------------------------------------------
__global__ __launch_bounds__(512, 2) void k_energy(
        const _Float16* __restrict__ Qf, const _Float16* __restrict__ Kf,
        unsigned short* __restrict__ S, const int* __restrict__ dkp) {
    __shared__ _Float16 sA[3][SLOT];
    __shared__ _Float16 sB[3][SLOT];
    const int i = blockIdx.x;
    const int b = i / 36;
    int t = i - b * 36;
    int by = 0;
    while (t >= by + 1) { t -= by + 1; by++; }  // triangle decode: bx=t <= by
    gemm_body<2>(t, by, b, Qf, Kf, S, nullptr, dkp,
                 Hc, Hc, (size_t)Tc * Hc, (size_t)Tc * Hc, (size_t)Tc * Tc, 32,
                 sA[0], sB[0]);
}

// ---------------------------------------------------------------------------
// k_pv: PV, grid (4, 8, batch); nkt = (by+1)*8 inside body.  P is f16.
// ---------------------------------------------------------------------------
__global__ __launch_bounds__(512, 2) void k_pv(
        const _Float16* __restrict__ S, const _Float16* __restrict__ Vt,
        float* __restrict__ out, const int* __restrict__ dkp) {
    __shared__ _Float16 sA[3][SLOT];
    __shared__ _Float16 sB[3][SLOT];
    gemm_body<3>(blockIdx.x, blockIdx.y, blockIdx.z, S, Vt, out, nullptr, dkp,
                 Tc, Tc, (size_t)Tc * Tc, (size_t)Hc * Tc, (size_t)Tc * Hc, 0,
                 sA[0], sB[0]);
}

// ---------------------------------------------------------------------------
// softmax_k: one block per (b,q) row.  f16 logits in, f16 P out (in place).
// Threads beyond the tile-aligned causal extent skip loads/stores (PV never
// reads those cols) but participate in reductions.
// ---------------------------------------------------------------------------
__global__ __launch_bounds__(256) void softmax_k(unsigned short* __restrict__ S) {
    const int q = blockIdx.x & (Tc - 1);
    const int b = blockIdx.x >> 11;
    const int tid = threadIdx.x;
    const int c0 = tid * 8;
    const int limit = ((q >> 8) + 1) << 8;  // tile-aligned causal extent
    const bool active = c0 < limit;
    unsigned short* row = S + ((size_t)b * Tc + q) * Tc;

    float v[8];
    if (active) {
        uint4 raw = *reinterpret_cast<const uint4*>(row + c0);
        unsigned u[4] = {raw.x, raw.y, raw.z, raw.w};
#pragma unroll
        for (int p = 0; p < 4; p++) {
            v[2 * p]     = f16val((unsigned short)(u[p] & 0xFFFFu));
            v[2 * p + 1] = f16val((unsigned short)(u[p] >> 16));
        }
#pragma unroll
        for (int i = 0; i < 8; i++)
            if (c0 + i > q) v[i] = -INFINITY;
    } else {
#pragma unroll
        for (int i = 0; i < 8; i++) v[i] = -INFINITY;
    }

    float m = v[0];
#pragma unroll
    for (int i = 1; i < 8; i++) m = fmaxf(m, v[i]);
#pragma unroll
    for (int off = 1; off < 64; off <<= 1) m = fmaxf(m, __shfl_xor(m, off));
    __shared__ float red[4];
    if ((tid & 63) == 0) red[tid >> 6] = m;
    __syncthreads();
    m = fmaxf(fmaxf(red[0], red[1]), fmaxf(red[2], red[3]));

    float e[8], s = 0.f;
#pragma unroll
    for (int i = 0; i < 8; i++) {
        e[i] = __expf(v[i] - m);  // exp(-inf)=0
        s += e[i];
    }
#pragma unroll
    for (int off = 1; off < 64; off <<= 1) s += __shfl_xor(s, off);
    __syncthreads();
    if ((tid & 63) == 0) red[tid >> 6] = s;
    __syncthreads();
    s = red[0] + red[1] + red[2] + red[3];
    const float inv = 1.0f / s;

    if (active) {
        unsigned o[4];
#pragma unroll
        for (int p = 0; p < 4; p++) {
            unsigned short a = f16bits(e[2 * p] * inv);
            unsigned short bb = f16bits(e[2 * p + 1] * inv);
            o[p] = (unsigned)a | ((unsigned)bb << 16);
        }
        uint4 w; w.x = o[0]; w.y = o[1]; w.z = o[2]; w.w = o[3];
        *reinterpret_cast<uint4*>(row + c0) = w;
    }
}

// ---------------------------------------------------------------------------
extern "C" void kernel_launch(void* const* d_in, const int* in_sizes, int n_in,
                              void* d_out, int out_size, void* d_ws, size_t ws_size,
                              hipStream_t stream) {
    const float* x  = (const float*)d_in[0];
    const float* Wq = (const float*)d_in[1];
    const float* Wk = (const float*)d_in[2];
    const float* Wv = (const float*)d_in[3];
    const int*   dk = (const int*)d_in[4];
    float* out = (float*)d_out;
    char* ws = (char*)d_ws;

    const size_t SZ_XE = (size_t)Mc * Ec * 2;  // 32 MiB (f16 [16384][1024])
    const size_t SZ_W  = (size_t)Ec * Hc * 2;  // 2 MiB

    // Layout: persistent buffers first, prep buffers last so S can alias them.
    size_t o = 0;
    auto nxt = [&](size_t bytes) { void* p = ws + o; o += bytes; return p; };
    _Float16* Qf   = (_Float16*)nxt(SZ_XE);
    _Float16* Kf   = (_Float16*)nxt(SZ_XE);
    _Float16* Vt   = (_Float16*)nxt(SZ_XE);
    _Float16* Xf   = (_Float16*)nxt(SZ_XE);
    _Float16* Wall = (_Float16*)nxt(3 * SZ_W);  // [3072][1024] = Wq|Wk|Wv, transposed
    // S: all-batch f16 [8][2048][2048] = 64 MiB, aliases Xf+Wall+26MiB beyond
    // (Xf and Wall are dead once k_qkv completes; k_energy is stream-ordered).
    unsigned short* S = (unsigned short*)Xf;
    (void)ws_size; (void)in_sizes; (void)n_in; (void)out_size;

    prep_x<<<(Mc * Ec / 4 + 255) / 256, 256, 0, stream>>>(x, Xf, Mc * Ec);
    prep_w<<<dim3(32, 32, 3), 256, 0, stream>>>(Wq, Wk, Wv, Wall);

    // Q, K, V projections: single-term f16, K=1024
    k_qkv<<<768, 512, 0, stream>>>(Xf, Wall, Qf, Kf, Vt, dk);

    // energy: 288 causal tiles, f16 logits, single-term K=1024
    k_energy<<<288, 512, 0, stream>>>(Qf, Kf, (unsigned short*)S, dk);

    softmax_k<<<Bc * Tc, 256, 0, stream>>>((unsigned short*)S);

    // PV: nkt=(by+1)*8 per tile (P beyond causal edge is 0)
    k_pv<<<dim3(4, 8, Bc), 512, 0, stream>>>((const _Float16*)S, Vt, out, dk);
}